// Round 5
// baseline (833.360 us; speedup 1.0000x reference)
//
#include <hip/hip_runtime.h>

// ---------------------------------------------------------------------------
// K1 (VALU, cross-validated vs MFMA version): mod[b,ff] = xt * silu(xg)
// ---------------------------------------------------------------------------
__global__ __launch_bounds__(256) void k1_valu(
    const float* __restrict__ x,
    const float* __restrict__ Wt,
    const float* __restrict__ Wg,
    float* __restrict__ mod)
{
  __shared__ __align__(16) float xs[64 * 132];
  const int tid = threadIdx.x;
  const int b   = tid & 63;
  const int fqu = __builtin_amdgcn_readfirstlane(tid >> 6);
  const int ffbase = blockIdx.x * 16 + fqu * 4;

  float accT[4] = {0.f, 0.f, 0.f, 0.f};
  float accG[4] = {0.f, 0.f, 0.f, 0.f};

  for (int kc = 0; kc < 1024; kc += 128) {
    __syncthreads();
    #pragma unroll
    for (int q = 0; q < 8; ++q) {
      int idx4 = q * 256 + tid;
      int row  = idx4 >> 5;
      int c4   = idx4 & 31;
      float4 v = *reinterpret_cast<const float4*>(x + row * 1024 + kc + c4 * 4);
      *reinterpret_cast<float4*>(&xs[row * 132 + c4 * 4]) = v;
    }
    __syncthreads();

    const float* wt0 = Wt + ffbase * 1024 + kc;
    const float* wg0 = Wg + ffbase * 1024 + kc;
    #pragma unroll 8
    for (int j = 0; j < 128; j += 4) {
      float4 xv = *reinterpret_cast<const float4*>(&xs[b * 132 + j]);
      #pragma unroll
      for (int f = 0; f < 4; ++f) {
        const float* wt = wt0 + f * 1024 + j;
        const float* wg = wg0 + f * 1024 + j;
        accT[f] += xv.x * wt[0] + xv.y * wt[1] + xv.z * wt[2] + xv.w * wt[3];
        accG[f] += xv.x * wg[0] + xv.y * wg[1] + xv.z * wg[2] + xv.w * wg[3];
      }
    }
  }

  #pragma unroll
  for (int f = 0; f < 4; ++f) {
    float t = accT[f], g = accG[f];
    float sig = 1.0f / (1.0f + __expf(-g));
    mod[b * 8192 + ffbase + f] = t * g * sig;
  }
}

// ---------------------------------------------------------------------------
// K1b: s[b*4+k] = rsqrt(mean(|mod[b,k,:]|) + eps)
// ---------------------------------------------------------------------------
__global__ __launch_bounds__(256) void k1b_scale(const float* __restrict__ mod,
                                                 float* __restrict__ s)
{
  const int row = blockIdx.x;
  const int tid = threadIdx.x;
  const float* p = mod + row * 2048;
  float sum = 0.0f;
  #pragma unroll
  for (int q = 0; q < 8; ++q) sum += fabsf(p[q * 256 + tid]);
  #pragma unroll
  for (int o = 1; o < 64; o <<= 1) sum += __shfl_xor(sum, o, 64);
  __shared__ float ls[4];
  if ((tid & 63) == 0) ls[tid >> 6] = sum;
  __syncthreads();
  if (tid == 0) {
    float t = ls[0] + ls[1] + ls[2] + ls[3];
    s[row] = rsqrtf(t * (1.0f / 2048.0f) + 1e-4f);
  }
}

// ---------------------------------------------------------------------------
// K1c: modn[b,ff] = mod[b,ff] * s[b*4 + ff/2048]   (normalized mod)
// ---------------------------------------------------------------------------
__global__ __launch_bounds__(256) void k1c_norm(const float* __restrict__ mod,
                                                const float* __restrict__ s,
                                                float* __restrict__ modn)
{
  int g = blockIdx.x * 256 + threadIdx.x;   // 64*8192 threads
  int b = g >> 13;
  int ff = g & 8191;
  int k = ff >> 11;
  modn[g] = mod[g] * s[b * 4 + k];
}

// ---------------------------------------------------------------------------
// K2 (paranoid-simple): one thread per (b,i,j), k=0,1 planes -> magsum[b]
// ---------------------------------------------------------------------------
__global__ __launch_bounds__(256) void k2_mag(
    const float* __restrict__ modn,
    const float* __restrict__ wstat,
    const float* __restrict__ wmod,
    const float* __restrict__ cw,
    const float* __restrict__ cb,
    float* __restrict__ magsum)
{
  int g = blockIdx.x * 256 + threadIdx.x;   // 64*65536 threads
  int b = g >> 16;
  int ij = g & 65535;
  int i = ij >> 8, j = ij & 255;

  float weff[4]; float beff = 0.0f;
  #pragma unroll
  for (int r = 0; r < 4; ++r) {
    weff[r] = cw[r] + cw[4 + r] + cw[8 + r] + cw[12 + r];
    beff += cb[r];
  }
  const float* mb = modn + b * 8192;

  float m[2];
  #pragma unroll
  for (int k = 0; k < 2; ++k) {
    float d = 0.0f;
    #pragma unroll
    for (int r = 0; r < 4; ++r)
      d += weff[r] * mb[k * 2048 + r * 512 + i] * mb[k * 2048 + r * 512 + 256 + j];
    m[k] = wmod[k * 65536 + ij] * (d + beff);
  }
  float A1r = wstat[131072 + ij * 2];
  float A1i = wstat[131072 + ij * 2 + 1];
  float re = A1r * m[0] - A1i * m[1];
  float im = A1r * m[1] - A1i * m[0];
  float mag = sqrtf(re * re + im * im + 1e-4f);

  #pragma unroll
  for (int o = 1; o < 64; o <<= 1) mag += __shfl_xor(mag, o, 64);
  if ((threadIdx.x & 63) == 0) atomicAdd(&magsum[b], mag);
}

// ---------------------------------------------------------------------------
// K4 (paranoid-simple): one thread per (b,i,j), full epilogue, FP32 store
// ---------------------------------------------------------------------------
__global__ __launch_bounds__(256) void k4_out(
    const float* __restrict__ modn,
    const float* __restrict__ wstat,
    const float* __restrict__ wmod,
    const float* __restrict__ cw,
    const float* __restrict__ cb,
    const float* __restrict__ magsum,
    float* __restrict__ out)
{
  int g = blockIdx.x * 256 + threadIdx.x;   // 64*65536 threads
  int b = g >> 16;
  int ij = g & 65535;
  int i = ij >> 8, j = ij & 255;

  float weff[4]; float beff = 0.0f;
  #pragma unroll
  for (int r = 0; r < 4; ++r) {
    weff[r] = cw[r] + cw[4 + r] + cw[8 + r] + cw[12 + r];
    beff += cb[r];
  }
  const float* mb = modn + b * 8192;

  float m[4];
  #pragma unroll
  for (int k = 0; k < 4; ++k) {
    float d = 0.0f;
    #pragma unroll
    for (int r = 0; r < 4; ++r)
      d += weff[r] * mb[k * 2048 + r * 512 + i] * mb[k * 2048 + r * 512 + 256 + j];
    m[k] = wmod[k * 65536 + ij] * (d + beff);
  }
  float A0r = wstat[ij * 2];
  float A0i = wstat[ij * 2 + 1];
  float A1r = wstat[131072 + ij * 2];
  float A1i = wstat[131072 + ij * 2 + 1];
  float re = A1r * m[0] - A1i * m[1];
  float im = A1r * m[1] - A1i * m[0];
  float inv = rsqrtf(magsum[b] * (1.0f / 65536.0f) + 1e-4f);
  float mwre = A0r + re * inv;
  float mwim = A0i + im * inv;
  float den = sqrtf(m[2] * m[2] + m[3] * m[3] + 1e-4f);
  out[g] = (mwre * m[2] + mwim * m[3]) / den;
}

extern "C" void kernel_launch(void* const* d_in, const int* in_sizes, int n_in,
                              void* d_out, int out_size, void* d_ws, size_t ws_size,
                              hipStream_t stream) {
  const float* x     = (const float*)d_in[0];
  const float* Wt    = (const float*)d_in[1];
  const float* Wg    = (const float*)d_in[2];
  const float* wstat = (const float*)d_in[3];
  const float* wmod  = (const float*)d_in[4];
  const float* cw    = (const float*)d_in[5];
  const float* cb    = (const float*)d_in[6];

  float* mod    = (float*)d_ws;            // 524288 floats
  float* modn   = mod + 524288;            // 524288 floats
  float* sbuf   = modn + 524288;           // 256 floats
  float* magsum = sbuf + 256;              // 64 floats

  hipMemsetAsync(magsum, 0, 64 * sizeof(float), stream);
  k1_valu  <<<512, 256, 0, stream>>>(x, Wt, Wg, mod);
  k1b_scale<<<256, 256, 0, stream>>>(mod, sbuf);
  k1c_norm <<<2048, 256, 0, stream>>>(mod, sbuf, modn);
  k2_mag   <<<16384, 256, 0, stream>>>(modn, wstat, wmod, cw, cb, magsum);
  k4_out   <<<16384, 256, 0, stream>>>(modn, wstat, wmod, cw, cb, magsum,
                                       (float*)d_out);
}

// Round 6
// 176.692 us; speedup vs baseline: 4.7164x; 4.7164x over previous
//
#include <hip/hip_runtime.h>

typedef __bf16 bf16x8 __attribute__((ext_vector_type(8)));
typedef float floatx4 __attribute__((ext_vector_type(4)));

// split fp32 -> bf16 hi + bf16 lo (x ~= hi + lo, residual ~2^-17)
__device__ inline void cvt8_hl(const float* __restrict__ p, bf16x8& h, bf16x8& l){
  float4 v0 = *reinterpret_cast<const float4*>(p);
  float4 v1 = *reinterpret_cast<const float4*>(p + 4);
  float v[8] = {v0.x, v0.y, v0.z, v0.w, v1.x, v1.y, v1.z, v1.w};
  #pragma unroll
  for (int i = 0; i < 8; ++i) {
    __bf16 hi = (__bf16)v[i];
    h[i] = hi;
    l[i] = (__bf16)(v[i] - (float)hi);
  }
}

// ---------------------------------------------------------------------------
// K1: mod[b,ff] = xt * silu(xg), xt = x@Wt^T, xg = x@Wg^T. M=64,N=8192,K=1024.
// MFMA 16x16x32 bf16, split-precision hi/lo (hh+hl+lh) for fp32-class accuracy.
// Fragments loaded straight from global (row-major layouts match A/B lane
// maps: A[m=lane&15][k=quad*8+j], B[n=lane&15][k=quad*8+j], D col=lane&15,
// row=quad*4+reg). 32 ff/block, split-K=2 across wave pairs, LDS combine.
// Grid=256 blocks so all CUs stream W (67 MB fp32, read exactly once).
// ---------------------------------------------------------------------------
__global__ __launch_bounds__(256) void k1_gemm(
    const float* __restrict__ x,
    const float* __restrict__ Wt,
    const float* __restrict__ Wg,
    float* __restrict__ mod)
{
  __shared__ float red[2][32][64];   // [ffgrp][acc-slot][lane]
  const int tid  = threadIdx.x;
  const int wave = tid >> 6, lane = tid & 63;
  const int quad = lane >> 4, r16 = lane & 15;
  const int ffgrp = wave & 1, khalf = wave >> 1;
  const int ff = blockIdx.x * 32 + ffgrp * 16 + r16;
  const int kb = khalf * 512 + quad * 8;

  floatx4 accT[4], accG[4];
  #pragma unroll
  for (int m = 0; m < 4; ++m) { accT[m] = (floatx4)0.0f; accG[m] = (floatx4)0.0f; }

  const float* wt = Wt + ff * 1024 + kb;
  const float* wg = Wg + ff * 1024 + kb;
  const float* xp = x  + r16 * 1024 + kb;

  #pragma unroll 2
  for (int it = 0; it < 16; ++it) {
    const int ko = it * 32;
    bf16x8 bth, btl, bgh, bgl;
    cvt8_hl(wt + ko, bth, btl);
    cvt8_hl(wg + ko, bgh, bgl);
    #pragma unroll
    for (int mt = 0; mt < 4; ++mt) {
      bf16x8 ah, al;
      cvt8_hl(xp + mt * 16384 + ko, ah, al);
      accT[mt] = __builtin_amdgcn_mfma_f32_16x16x32_bf16(ah, bth, accT[mt], 0, 0, 0);
      accT[mt] = __builtin_amdgcn_mfma_f32_16x16x32_bf16(ah, btl, accT[mt], 0, 0, 0);
      accT[mt] = __builtin_amdgcn_mfma_f32_16x16x32_bf16(al, bth, accT[mt], 0, 0, 0);
      accG[mt] = __builtin_amdgcn_mfma_f32_16x16x32_bf16(ah, bgh, accG[mt], 0, 0, 0);
      accG[mt] = __builtin_amdgcn_mfma_f32_16x16x32_bf16(ah, bgl, accG[mt], 0, 0, 0);
      accG[mt] = __builtin_amdgcn_mfma_f32_16x16x32_bf16(al, bgh, accG[mt], 0, 0, 0);
    }
  }

  if (khalf == 1) {
    #pragma unroll
    for (int mt = 0; mt < 4; ++mt)
      #pragma unroll
      for (int r = 0; r < 4; ++r) {
        red[ffgrp][mt * 4 + r][lane]      = accT[mt][r];
        red[ffgrp][16 + mt * 4 + r][lane] = accG[mt][r];
      }
  }
  __syncthreads();
  if (khalf == 0) {
    #pragma unroll
    for (int mt = 0; mt < 4; ++mt) {
      #pragma unroll
      for (int r = 0; r < 4; ++r) {
        float t = accT[mt][r] + red[ffgrp][mt * 4 + r][lane];
        float g = accG[mt][r] + red[ffgrp][16 + mt * 4 + r][lane];
        float sig = 1.0f / (1.0f + __expf(-g));
        int b = mt * 16 + quad * 4 + r;          // C/D: row = quad*4 + reg
        mod[b * 8192 + ff] = t * g * sig;
      }
    }
  }
}

// ---------------------------------------------------------------------------
// K1b: s[b*4+k] = rsqrt(mean(|mod[b,k,:]|) + eps)
// ---------------------------------------------------------------------------
__global__ __launch_bounds__(256) void k1b_scale(const float* __restrict__ mod,
                                                 float* __restrict__ s)
{
  const int row = blockIdx.x;
  const int tid = threadIdx.x;
  const float* p = mod + row * 2048;
  float sum = 0.0f;
  #pragma unroll
  for (int q = 0; q < 8; ++q) sum += fabsf(p[q * 256 + tid]);
  #pragma unroll
  for (int o = 1; o < 64; o <<= 1) sum += __shfl_xor(sum, o, 64);
  __shared__ float ls[4];
  if ((tid & 63) == 0) ls[tid >> 6] = sum;
  __syncthreads();
  if (tid == 0) {
    float t = ls[0] + ls[1] + ls[2] + ls[3];
    s[row] = rsqrtf(t * (1.0f / 2048.0f) + 1e-4f);
  }
}

// ---------------------------------------------------------------------------
// K2: partial[b*8+jc] = block sum of sqrt(re^2+im^2+eps). NO atomics (the
// round-5 531us stall was 65536 same-line cross-XCD atomic RMWs).
// ---------------------------------------------------------------------------
__global__ __launch_bounds__(256) void k2_mag(
    const float* __restrict__ mod, const float* __restrict__ s,
    const float* __restrict__ wstat,
    const float* __restrict__ wmod,
    const float* __restrict__ cw,
    const float* __restrict__ cb,
    float* __restrict__ partial)
{
  const int b = blockIdx.x, jc = blockIdx.y;
  const int tid = threadIdx.x;
  __shared__ __align__(16) float a_l[256 * 8];

  float weff[4]; float beff = 0.0f;
  #pragma unroll
  for (int r = 0; r < 4; ++r) {
    weff[r] = cw[r] + cw[4 + r] + cw[8 + r] + cw[12 + r];
    beff += cb[r];
  }
  const float s0 = s[b * 4 + 0], s1 = s[b * 4 + 1];
  const float* mb = mod + b * 8192;

  #pragma unroll
  for (int p = 0; p < 8; ++p) {              // p = (k,r); tid = i  (coalesced)
    int k = p >> 2, r = p & 3;
    float sc = (k ? s1 : s0) * weff[r];
    a_l[tid * 8 + p] = mb[k * 2048 + r * 512 + tid] * sc;
  }
  const int j = jc * 32 + (tid & 31);
  float bp[8];
  #pragma unroll
  for (int p = 0; p < 8; ++p) {
    int k = p >> 2, r = p & 3;
    bp[p] = mb[k * 2048 + r * 512 + 256 + j] * (k ? s1 : s0);
  }
  __syncthreads();

  const int ioff = tid >> 5;
  float acc = 0.0f;
  for (int it = 0; it < 32; ++it) {
    const int i = it * 8 + ioff;
    const float4 av0 = *reinterpret_cast<const float4*>(&a_l[i * 8]);
    const float4 av1 = *reinterpret_cast<const float4*>(&a_l[i * 8 + 4]);
    float d0 = av0.x * bp[0] + av0.y * bp[1] + av0.z * bp[2] + av0.w * bp[3];
    float d1 = av1.x * bp[4] + av1.y * bp[5] + av1.z * bp[6] + av1.w * bp[7];
    const int ij = i * 256 + j;
    float m0 = wmod[ij] * (d0 + beff);
    float m1 = wmod[65536 + ij] * (d1 + beff);
    float2 a1 = *reinterpret_cast<const float2*>(wstat + 131072 + ij * 2);
    float re = a1.x * m0 - a1.y * m1;
    float im = a1.x * m1 - a1.y * m0;
    acc += sqrtf(re * re + im * im + 1e-4f);
  }
  #pragma unroll
  for (int o = 1; o < 64; o <<= 1) acc += __shfl_xor(acc, o, 64);
  __shared__ float wsum[4];
  if ((tid & 63) == 0) wsum[tid >> 6] = acc;
  __syncthreads();
  if (tid == 0) partial[b * 8 + jc] = wsum[0] + wsum[1] + wsum[2] + wsum[3];
}

// ---------------------------------------------------------------------------
// K4: final output (fp32). grid (64 b, 8 i-chunks of 32). 2 j's per thread,
// float2 stores. magsum = sum of 8 partials in preamble (no extra kernel).
// ---------------------------------------------------------------------------
__global__ __launch_bounds__(256) void k4_out(
    const float* __restrict__ mod, const float* __restrict__ s,
    const float* __restrict__ wstat,
    const float* __restrict__ wmod,
    const float* __restrict__ cw,
    const float* __restrict__ cb,
    const float* __restrict__ partial,
    float* __restrict__ out)
{
  const int b = blockIdx.x, ibase = blockIdx.y * 32;
  const int tid = threadIdx.x;
  __shared__ __align__(16) float a_l[32 * 16];

  float weff[4]; float beff = 0.0f;
  #pragma unroll
  for (int r = 0; r < 4; ++r) {
    weff[r] = cw[r] + cw[4 + r] + cw[8 + r] + cw[12 + r];
    beff += cb[r];
  }
  float sk[4];
  #pragma unroll
  for (int k = 0; k < 4; ++k) sk[k] = s[b * 4 + k];
  const float* mb = mod + b * 8192;

  float tot = 0.0f;
  #pragma unroll
  for (int t = 0; t < 8; ++t) tot += partial[b * 8 + t];
  const float inv = rsqrtf(tot * (1.0f / 65536.0f) + 1e-4f);

  #pragma unroll
  for (int p = 0; p < 2; ++p) {
    int idx = p * 256 + tid;
    int il = idx & 31, kr = idx >> 5;
    int k = kr >> 2, r = kr & 3;
    a_l[il * 16 + kr] = mb[k * 2048 + r * 512 + ibase + il] * (sk[k] * weff[r]);
  }
  const int j = (tid & 127) * 2;
  const int ioff = tid >> 7;
  float bp0[16], bp1[16];
  #pragma unroll
  for (int kr = 0; kr < 16; ++kr) {
    int k = kr >> 2, r = kr & 3;
    float2 v = *reinterpret_cast<const float2*>(mb + k * 2048 + r * 512 + 256 + j);
    bp0[kr] = v.x * sk[k]; bp1[kr] = v.y * sk[k];
  }
  __syncthreads();

  #pragma unroll 2
  for (int it = 0; it < 16; ++it) {
    const int il = it * 2 + ioff;
    const int i = ibase + il;
    const float4 a0 = *reinterpret_cast<const float4*>(&a_l[il * 16]);
    const float4 a1 = *reinterpret_cast<const float4*>(&a_l[il * 16 + 4]);
    const float4 a2 = *reinterpret_cast<const float4*>(&a_l[il * 16 + 8]);
    const float4 a3 = *reinterpret_cast<const float4*>(&a_l[il * 16 + 12]);
    const int ij = i * 256 + j;
    const float2 wm0 = *reinterpret_cast<const float2*>(wmod + ij);
    const float2 wm1 = *reinterpret_cast<const float2*>(wmod + 65536 + ij);
    const float2 wm2 = *reinterpret_cast<const float2*>(wmod + 131072 + ij);
    const float2 wm3 = *reinterpret_cast<const float2*>(wmod + 196608 + ij);
    const float4 A0v = *reinterpret_cast<const float4*>(wstat + ij * 2);
    const float4 A1v = *reinterpret_cast<const float4*>(wstat + 131072 + ij * 2);
    float outv[2];
    #pragma unroll
    for (int e = 0; e < 2; ++e) {
      const float* bp = e ? bp1 : bp0;
      float d0 = a0.x * bp[0] + a0.y * bp[1] + a0.z * bp[2] + a0.w * bp[3];
      float d1 = a1.x * bp[4] + a1.y * bp[5] + a1.z * bp[6] + a1.w * bp[7];
      float d2 = a2.x * bp[8] + a2.y * bp[9] + a2.z * bp[10] + a2.w * bp[11];
      float d3 = a3.x * bp[12] + a3.y * bp[13] + a3.z * bp[14] + a3.w * bp[15];
      float m0 = (e ? wm0.y : wm0.x) * (d0 + beff);
      float m1 = (e ? wm1.y : wm1.x) * (d1 + beff);
      float m2 = (e ? wm2.y : wm2.x) * (d2 + beff);
      float m3 = (e ? wm3.y : wm3.x) * (d3 + beff);
      float A0r = e ? A0v.z : A0v.x;
      float A0i = e ? A0v.w : A0v.y;
      float A1r = e ? A1v.z : A1v.x;
      float A1i = e ? A1v.w : A1v.y;
      float re = A1r * m0 - A1i * m1;
      float im = A1r * m1 - A1i * m0;
      float mwre = A0r + re * inv;
      float mwim = A0i + im * inv;
      float rd = rsqrtf(m2 * m2 + m3 * m3 + 1e-4f);
      outv[e] = (mwre * m2 + mwim * m3) * rd;
    }
    *reinterpret_cast<float2*>(out + b * 65536 + ij) = make_float2(outv[0], outv[1]);
  }
}

extern "C" void kernel_launch(void* const* d_in, const int* in_sizes, int n_in,
                              void* d_out, int out_size, void* d_ws, size_t ws_size,
                              hipStream_t stream) {
  const float* x     = (const float*)d_in[0];
  const float* Wt    = (const float*)d_in[1];
  const float* Wg    = (const float*)d_in[2];
  const float* wstat = (const float*)d_in[3];
  const float* wmod  = (const float*)d_in[4];
  const float* cw    = (const float*)d_in[5];
  const float* cb    = (const float*)d_in[6];

  float* mod     = (float*)d_ws;           // 524288 floats
  float* sbuf    = mod + 524288;           // 256 floats
  float* partial = sbuf + 256;             // 512 floats

  k1_gemm  <<<256, 256, 0, stream>>>(x, Wt, Wg, mod);
  k1b_scale<<<256, 256, 0, stream>>>(mod, sbuf);
  k2_mag   <<<dim3(64, 8), 256, 0, stream>>>(mod, sbuf, wstat, wmod, cw, cb, partial);
  k4_out   <<<dim3(64, 8), 256, 0, stream>>>(mod, sbuf, wstat, wmod, cw, cb, partial,
                                             (float*)d_out);
}

// Round 7
// 152.218 us; speedup vs baseline: 5.4748x; 1.1608x over previous
//
#include <hip/hip_runtime.h>

typedef __bf16 bf16x8 __attribute__((ext_vector_type(8)));
typedef float floatx4 __attribute__((ext_vector_type(4)));

// split fp32 -> bf16 hi + bf16 lo (x ~= hi + lo, residual ~2^-17)
__device__ inline void cvt8_hl(const float* __restrict__ p, bf16x8& h, bf16x8& l){
  float4 v0 = *reinterpret_cast<const float4*>(p);
  float4 v1 = *reinterpret_cast<const float4*>(p + 4);
  float v[8] = {v0.x, v0.y, v0.z, v0.w, v1.x, v1.y, v1.z, v1.w};
  #pragma unroll
  for (int i = 0; i < 8; ++i) {
    __bf16 hi = (__bf16)v[i];
    h[i] = hi;
    l[i] = (__bf16)(v[i] - (float)hi);
  }
}

// ---------------------------------------------------------------------------
// K1: mod[b,ff] = xt * silu(xg). M=64, N=8192, K=1024. MFMA 16x16x32 bf16,
// split-precision hi/lo (hh+hl+lh). Round-6 fix: grid 256->512 (16 ff/block),
// split-K=4 across the block's 4 waves (K=256 each), full K-loop unroll for
// load hoisting. 2 blocks/CU, 8 waves/CU (was 1 block / 4 waves -> 10.6% occ,
// latency-bound at 59us).
// ---------------------------------------------------------------------------
__global__ __launch_bounds__(256) void k1_gemm(
    const float* __restrict__ x,
    const float* __restrict__ Wt,
    const float* __restrict__ Wg,
    float* __restrict__ mod)
{
  __shared__ float red[3][32][64];   // waves 1..3 partials, 24 KB
  const int tid  = threadIdx.x;
  const int wave = tid >> 6, lane = tid & 63;
  const int quad = lane >> 4, r16 = lane & 15;
  const int ff = blockIdx.x * 16 + r16;
  const int kb = wave * 256 + quad * 8;

  floatx4 accT[4], accG[4];
  #pragma unroll
  for (int m = 0; m < 4; ++m) { accT[m] = (floatx4)0.0f; accG[m] = (floatx4)0.0f; }

  const float* wt = Wt + ff * 1024 + kb;
  const float* wg = Wg + ff * 1024 + kb;
  const float* xp = x  + r16 * 1024 + kb;

  #pragma unroll
  for (int it = 0; it < 8; ++it) {
    const int ko = it * 32;
    bf16x8 bth, btl, bgh, bgl;
    cvt8_hl(wt + ko, bth, btl);
    cvt8_hl(wg + ko, bgh, bgl);
    #pragma unroll
    for (int mt = 0; mt < 4; ++mt) {
      bf16x8 ah, al;
      cvt8_hl(xp + mt * 16384 + ko, ah, al);
      accT[mt] = __builtin_amdgcn_mfma_f32_16x16x32_bf16(ah, bth, accT[mt], 0, 0, 0);
      accT[mt] = __builtin_amdgcn_mfma_f32_16x16x32_bf16(ah, btl, accT[mt], 0, 0, 0);
      accT[mt] = __builtin_amdgcn_mfma_f32_16x16x32_bf16(al, bth, accT[mt], 0, 0, 0);
      accG[mt] = __builtin_amdgcn_mfma_f32_16x16x32_bf16(ah, bgh, accG[mt], 0, 0, 0);
      accG[mt] = __builtin_amdgcn_mfma_f32_16x16x32_bf16(ah, bgl, accG[mt], 0, 0, 0);
      accG[mt] = __builtin_amdgcn_mfma_f32_16x16x32_bf16(al, bgh, accG[mt], 0, 0, 0);
    }
  }

  if (wave != 0) {
    #pragma unroll
    for (int mt = 0; mt < 4; ++mt)
      #pragma unroll
      for (int r = 0; r < 4; ++r) {
        red[wave - 1][mt * 4 + r][lane]      = accT[mt][r];
        red[wave - 1][16 + mt * 4 + r][lane] = accG[mt][r];
      }
  }
  __syncthreads();
  if (wave == 0) {
    #pragma unroll
    for (int mt = 0; mt < 4; ++mt) {
      #pragma unroll
      for (int r = 0; r < 4; ++r) {
        float t = accT[mt][r] + red[0][mt * 4 + r][lane]
                              + red[1][mt * 4 + r][lane]
                              + red[2][mt * 4 + r][lane];
        float g = accG[mt][r] + red[0][16 + mt * 4 + r][lane]
                              + red[1][16 + mt * 4 + r][lane]
                              + red[2][16 + mt * 4 + r][lane];
        float sig = 1.0f / (1.0f + __expf(-g));
        int b = mt * 16 + quad * 4 + r;          // C/D: row = quad*4 + reg
        mod[b * 8192 + ff] = t * g * sig;
      }
    }
  }
}

// ---------------------------------------------------------------------------
// K1b: s[b*4+k] = rsqrt(mean(|mod[b,k,:]|) + eps)
// ---------------------------------------------------------------------------
__global__ __launch_bounds__(256) void k1b_scale(const float* __restrict__ mod,
                                                 float* __restrict__ s)
{
  const int row = blockIdx.x;
  const int tid = threadIdx.x;
  const float* p = mod + row * 2048;
  float sum = 0.0f;
  #pragma unroll
  for (int q = 0; q < 8; ++q) sum += fabsf(p[q * 256 + tid]);
  #pragma unroll
  for (int o = 1; o < 64; o <<= 1) sum += __shfl_xor(sum, o, 64);
  __shared__ float ls[4];
  if ((tid & 63) == 0) ls[tid >> 6] = sum;
  __syncthreads();
  if (tid == 0) {
    float t = ls[0] + ls[1] + ls[2] + ls[3];
    s[row] = rsqrtf(t * (1.0f / 2048.0f) + 1e-4f);
  }
}

// ---------------------------------------------------------------------------
// K2: partial[b*8+jc] = block sum of sqrt(re^2+im^2+eps). No atomics.
// ---------------------------------------------------------------------------
__global__ __launch_bounds__(256) void k2_mag(
    const float* __restrict__ mod, const float* __restrict__ s,
    const float* __restrict__ wstat,
    const float* __restrict__ wmod,
    const float* __restrict__ cw,
    const float* __restrict__ cb,
    float* __restrict__ partial)
{
  const int b = blockIdx.x, jc = blockIdx.y;
  const int tid = threadIdx.x;
  __shared__ __align__(16) float a_l[256 * 8];

  float weff[4]; float beff = 0.0f;
  #pragma unroll
  for (int r = 0; r < 4; ++r) {
    weff[r] = cw[r] + cw[4 + r] + cw[8 + r] + cw[12 + r];
    beff += cb[r];
  }
  const float s0 = s[b * 4 + 0], s1 = s[b * 4 + 1];
  const float* mb = mod + b * 8192;

  #pragma unroll
  for (int p = 0; p < 8; ++p) {              // p = (k,r); tid = i  (coalesced)
    int k = p >> 2, r = p & 3;
    float sc = (k ? s1 : s0) * weff[r];
    a_l[tid * 8 + p] = mb[k * 2048 + r * 512 + tid] * sc;
  }
  const int j = jc * 32 + (tid & 31);
  float bp[8];
  #pragma unroll
  for (int p = 0; p < 8; ++p) {
    int k = p >> 2, r = p & 3;
    bp[p] = mb[k * 2048 + r * 512 + 256 + j] * (k ? s1 : s0);
  }
  __syncthreads();

  const int ioff = tid >> 5;
  float acc = 0.0f;
  for (int it = 0; it < 32; ++it) {
    const int i = it * 8 + ioff;
    const float4 av0 = *reinterpret_cast<const float4*>(&a_l[i * 8]);
    const float4 av1 = *reinterpret_cast<const float4*>(&a_l[i * 8 + 4]);
    float d0 = av0.x * bp[0] + av0.y * bp[1] + av0.z * bp[2] + av0.w * bp[3];
    float d1 = av1.x * bp[4] + av1.y * bp[5] + av1.z * bp[6] + av1.w * bp[7];
    const int ij = i * 256 + j;
    float m0 = wmod[ij] * (d0 + beff);
    float m1 = wmod[65536 + ij] * (d1 + beff);
    float2 a1 = *reinterpret_cast<const float2*>(wstat + 131072 + ij * 2);
    float re = a1.x * m0 - a1.y * m1;
    float im = a1.x * m1 - a1.y * m0;
    acc += sqrtf(re * re + im * im + 1e-4f);
  }
  #pragma unroll
  for (int o = 1; o < 64; o <<= 1) acc += __shfl_xor(acc, o, 64);
  __shared__ float wsum[4];
  if ((tid & 63) == 0) wsum[tid >> 6] = acc;
  __syncthreads();
  if (tid == 0) partial[b * 8 + jc] = wsum[0] + wsum[1] + wsum[2] + wsum[3];
}

// ---------------------------------------------------------------------------
// K4: final output (fp32). grid (64 b, 8 i-chunks of 32). 2 j's per thread,
// float2 stores. magsum = sum of 8 partials in preamble.
// ---------------------------------------------------------------------------
__global__ __launch_bounds__(256) void k4_out(
    const float* __restrict__ mod, const float* __restrict__ s,
    const float* __restrict__ wstat,
    const float* __restrict__ wmod,
    const float* __restrict__ cw,
    const float* __restrict__ cb,
    const float* __restrict__ partial,
    float* __restrict__ out)
{
  const int b = blockIdx.x, ibase = blockIdx.y * 32;
  const int tid = threadIdx.x;
  __shared__ __align__(16) float a_l[32 * 16];

  float weff[4]; float beff = 0.0f;
  #pragma unroll
  for (int r = 0; r < 4; ++r) {
    weff[r] = cw[r] + cw[4 + r] + cw[8 + r] + cw[12 + r];
    beff += cb[r];
  }
  float sk[4];
  #pragma unroll
  for (int k = 0; k < 4; ++k) sk[k] = s[b * 4 + k];
  const float* mb = mod + b * 8192;

  float tot = 0.0f;
  #pragma unroll
  for (int t = 0; t < 8; ++t) tot += partial[b * 8 + t];
  const float inv = rsqrtf(tot * (1.0f / 65536.0f) + 1e-4f);

  #pragma unroll
  for (int p = 0; p < 2; ++p) {
    int idx = p * 256 + tid;
    int il = idx & 31, kr = idx >> 5;
    int k = kr >> 2, r = kr & 3;
    a_l[il * 16 + kr] = mb[k * 2048 + r * 512 + ibase + il] * (sk[k] * weff[r]);
  }
  const int j = (tid & 127) * 2;
  const int ioff = tid >> 7;
  float bp0[16], bp1[16];
  #pragma unroll
  for (int kr = 0; kr < 16; ++kr) {
    int k = kr >> 2, r = kr & 3;
    float2 v = *reinterpret_cast<const float2*>(mb + k * 2048 + r * 512 + 256 + j);
    bp0[kr] = v.x * sk[k]; bp1[kr] = v.y * sk[k];
  }
  __syncthreads();

  #pragma unroll 2
  for (int it = 0; it < 16; ++it) {
    const int il = it * 2 + ioff;
    const int i = ibase + il;
    const float4 a0 = *reinterpret_cast<const float4*>(&a_l[il * 16]);
    const float4 a1 = *reinterpret_cast<const float4*>(&a_l[il * 16 + 4]);
    const float4 a2 = *reinterpret_cast<const float4*>(&a_l[il * 16 + 8]);
    const float4 a3 = *reinterpret_cast<const float4*>(&a_l[il * 16 + 12]);
    const int ij = i * 256 + j;
    const float2 wm0 = *reinterpret_cast<const float2*>(wmod + ij);
    const float2 wm1 = *reinterpret_cast<const float2*>(wmod + 65536 + ij);
    const float2 wm2 = *reinterpret_cast<const float2*>(wmod + 131072 + ij);
    const float2 wm3 = *reinterpret_cast<const float2*>(wmod + 196608 + ij);
    const float4 A0v = *reinterpret_cast<const float4*>(wstat + ij * 2);
    const float4 A1v = *reinterpret_cast<const float4*>(wstat + 131072 + ij * 2);
    float outv[2];
    #pragma unroll
    for (int e = 0; e < 2; ++e) {
      const float* bp = e ? bp1 : bp0;
      float d0 = a0.x * bp[0] + a0.y * bp[1] + a0.z * bp[2] + a0.w * bp[3];
      float d1 = a1.x * bp[4] + a1.y * bp[5] + a1.z * bp[6] + a1.w * bp[7];
      float d2 = a2.x * bp[8] + a2.y * bp[9] + a2.z * bp[10] + a2.w * bp[11];
      float d3 = a3.x * bp[12] + a3.y * bp[13] + a3.z * bp[14] + a3.w * bp[15];
      float m0 = (e ? wm0.y : wm0.x) * (d0 + beff);
      float m1 = (e ? wm1.y : wm1.x) * (d1 + beff);
      float m2 = (e ? wm2.y : wm2.x) * (d2 + beff);
      float m3 = (e ? wm3.y : wm3.x) * (d3 + beff);
      float A0r = e ? A0v.z : A0v.x;
      float A0i = e ? A0v.w : A0v.y;
      float A1r = e ? A1v.z : A1v.x;
      float A1i = e ? A1v.w : A1v.y;
      float re = A1r * m0 - A1i * m1;
      float im = A1r * m1 - A1i * m0;
      float mwre = A0r + re * inv;
      float mwim = A0i + im * inv;
      float rd = rsqrtf(m2 * m2 + m3 * m3 + 1e-4f);
      outv[e] = (mwre * m2 + mwim * m3) * rd;
    }
    *reinterpret_cast<float2*>(out + b * 65536 + ij) = make_float2(outv[0], outv[1]);
  }
}

extern "C" void kernel_launch(void* const* d_in, const int* in_sizes, int n_in,
                              void* d_out, int out_size, void* d_ws, size_t ws_size,
                              hipStream_t stream) {
  const float* x     = (const float*)d_in[0];
  const float* Wt    = (const float*)d_in[1];
  const float* Wg    = (const float*)d_in[2];
  const float* wstat = (const float*)d_in[3];
  const float* wmod  = (const float*)d_in[4];
  const float* cw    = (const float*)d_in[5];
  const float* cb    = (const float*)d_in[6];

  float* mod     = (float*)d_ws;           // 524288 floats
  float* sbuf    = mod + 524288;           // 256 floats
  float* partial = sbuf + 256;             // 512 floats

  k1_gemm  <<<512, 256, 0, stream>>>(x, Wt, Wg, mod);
  k1b_scale<<<256, 256, 0, stream>>>(mod, sbuf);
  k2_mag   <<<dim3(64, 8), 256, 0, stream>>>(mod, sbuf, wstat, wmod, cw, cb, partial);
  k4_out   <<<dim3(64, 8), 256, 0, stream>>>(mod, sbuf, wstat, wmod, cw, cb, partial,
                                             (float*)d_out);
}